// Round 6
// baseline (2879.492 us; speedup 1.0000x reference)
//
#include <hip/hip_runtime.h>
#include <math.h>

// Elman RNN, two-phase.
//   Phase 1 (parallel, all CUs): z = x*W1^T + b1 + b2 (f32-exact, 3-product
//     hi/lo bf16 MFMA), stored in MFMA C-fragment order INTO the h_seq
//     region of d_out (slab-aligned: z(s,tile) occupies exactly the 8KB that
//     h_seq(s,tile-rows) later overwrites; z(s) is consumed 2 steps before
//     h_seq(s) is written).
//   Phase 2 (serial, 32 blocks x 2 waves): h_t = tanh(h_{t-1}*W2^T + z_t).
//     ROUND-5 LESSON: this RNN amplifies per-step h error ~500x over 2048
//     steps (r4: eps=2^-17 -> 0.0039; r5: eps=2^-10 -> 1.6). h therefore
//     stays hi+lo bf16 with the r4-proven 3-product scheme:
//       W2hi*h_hi + W2hi*h_lo + W2lo*h_hi.
//     ROUND-4 LESSON: 8 waves re-reading the h plane was LDS-issue-bound
//     (96 ds_read_b128/step/CU). Now W=2 waves own 64 units each: 16 reads +
//     16 dword writes per CU-step. h plane stored f32 (no write-side pack);
//     hi/lo fragments built on read via v_perm_b32 (+sub for lo).
//     z prefetched 2 steps ahead; h_seq stores never drained in-loop.

#define S_LEN 2048
#define B_SZ  512
#define I_SZ  64
#define H_SZ  128
#define BT    16
#define NTILE 32
#define BLK1  512
#define BLK2  128
#define SBH   (B_SZ * H_SZ)      // floats per step-slab in out

typedef short bf16x8 __attribute__((ext_vector_type(8)));
typedef float f32x4  __attribute__((ext_vector_type(4)));

#define MFMA(A, B, C) __builtin_amdgcn_mfma_f32_16x16x32_bf16((A), (B), (C), 0, 0, 0)

#define LDS_BARRIER()                                        \
    asm volatile("s_waitcnt lgkmcnt(0)" ::: "memory");       \
    __builtin_amdgcn_s_barrier();                            \
    asm volatile("" ::: "memory")

__device__ __forceinline__ unsigned fbits(float v) {
    union { float f; unsigned u; } x; x.f = v; return x.u;
}
__device__ __forceinline__ float fval(unsigned u) {
    union { float f; unsigned u; } x; x.u = u; return x.f;
}
__device__ __forceinline__ unsigned short bf_rnd(float v) {   // round-half-up
    return (unsigned short)((fbits(v) + 0x8000u) >> 16);
}
__device__ __forceinline__ unsigned short bf_trunc(float v) {
    return (unsigned short)(fbits(v) >> 16);
}
// split 8 consecutive floats into hi/lo bf16 fragments (trunc, r4-proven)
__device__ __forceinline__ void split8t(float4 a, float4 b, bf16x8* hi, bf16x8* lo) {
    float v[8] = {a.x, a.y, a.z, a.w, b.x, b.y, b.z, b.w};
    #pragma unroll
    for (int j = 0; j < 8; ++j) {
        unsigned short h = bf_trunc(v[j]);
        (*hi)[j] = (short)h;
        (*lo)[j] = (short)bf_trunc(v[j] - fval(((unsigned)h) << 16));
    }
}

// ---------------- Phase 1: z = x*W1^T + b1 + b2 (fragment layout) ----------
__global__ __launch_bounds__(BLK1) void rnn_prepass(
    const float* __restrict__ x,
    const float* __restrict__ W1,
    const float* __restrict__ b1,
    const float* __restrict__ b2,
    float* __restrict__ z)
{
    const int tid  = threadIdx.x;
    const int lane = tid & 63;
    const int w    = tid >> 6;
    const int l15  = lane & 15;
    const int l4   = lane >> 4;
    const int unit = (w << 4) + l15;
    const int bid  = blockIdx.x;          // = s*32 + tile
    const int s    = bid >> 5;
    const int b0   = (bid & 31) << 4;

    // W1 B-fragments, hi/lo (3-product -> z is ~f32-exact)
    bf16x8 w1h[2], w1l[2];
    #pragma unroll
    for (int c = 0; c < 2; ++c) {
        const float* wr = W1 + unit * I_SZ + 32 * c + l4 * 8;
        split8t(*(const float4*)wr, *(const float4*)(wr + 4), &w1h[c], &w1l[c]);
    }
    const float zb = b1[unit] + b2[unit];

    // x A-fragments: row l15, k = 32c + l4*8 + j (same k-map as B -> exact)
    bf16x8 xh[2], xl[2];
    const float* xr = x + ((size_t)s * B_SZ + b0 + l15) * I_SZ + l4 * 8;
    #pragma unroll
    for (int c = 0; c < 2; ++c)
        split8t(*(const float4*)(xr + 32 * c), *(const float4*)(xr + 32 * c + 4),
                &xh[c], &xl[c]);

    f32x4 acc  = {zb, zb, zb, zb};
    f32x4 acc2 = {0.f, 0.f, 0.f, 0.f};
    acc  = MFMA(xh[0], w1h[0], acc);   acc  = MFMA(xh[1], w1h[1], acc);
    acc2 = MFMA(xl[0], w1h[0], acc2);  acc2 = MFMA(xl[1], w1h[1], acc2);
    acc2 = MFMA(xh[0], w1l[0], acc2);  acc2 = MFMA(xh[1], w1l[1], acc2);
    acc += acc2;

    // fragment-order store: subtile w of slab (s,tile), 1 KiB per wave
    *(f32x4*)(z + ((size_t)bid * 8 + w) * 256 + lane * 4) = acc;
}

// ---------------- Phase 2: serial recurrence (2 waves / tile) --------------
__global__ __launch_bounds__(BLK2, 1) void rnn_recur(
    const float* __restrict__ W2,
    const float* __restrict__ zr,     // z region (fragment layout) == out
    float* __restrict__ out)
{
    const int tid  = threadIdx.x;
    const int lane = tid & 63;
    const int w    = tid >> 6;        // wave 0..1 -> units [64w, 64w+64)
    const int l15  = lane & 15;
    const int l4   = lane >> 4;
    const int tile = blockIdx.x;
    const int b0   = tile << 4;

    __shared__ float hplane[2][BT * H_SZ];   // f32 h, swizzled, 2 x 8 KiB

    // ---- W2 B-fragments hi/lo: 4 subtiles x 4 k-chunks (128 VGPR) ----
    bf16x8 w2h[4][4], w2l[4][4];
    #pragma unroll
    for (int t = 0; t < 4; ++t) {
        const int n = (w << 6) + (t << 4) + l15;
        #pragma unroll
        for (int c = 0; c < 4; ++c) {
            const float* wr = W2 + n * H_SZ + 32 * c + l4 * 8;
            split8t(*(const float4*)wr, *(const float4*)(wr + 4),
                    &w2h[t][c], &w2l[t][c]);
        }
    }

    // ---- LDS byte offsets (swizzle: byte_in_row ^= (row&7)<<4) ----
    int rb[4][2];                 // read: chunk c, half hh (2 x b128 / chunk)
    #pragma unroll
    for (int c = 0; c < 4; ++c)
        #pragma unroll
        for (int hh = 0; hh < 2; ++hh)
            rb[c][hh] = l15 * 512 +
                ((((32 * c + l4 * 8 + 4 * hh) << 2)) ^ ((l15 & 7) << 4));
    int wb[4][4];                 // write: subtile t, reg r (row = l4*4+r)
    #pragma unroll
    for (int t = 0; t < 4; ++t)
        #pragma unroll
        for (int r = 0; r < 4; ++r) {
            int row = (l4 << 2) + r;
            wb[t][r] = row * 512 +
                ((((w << 6) + (t << 4) + l15) << 2) ^ ((row & 7) << 4));
        }

    // ---- pointers: z (fragment layout), h_seq (standard layout) ----
    const float* zp = zr + (size_t)tile * 2048 + (size_t)(4 * w) * 256 + lane * 4;
    const size_t obase = (size_t)(b0 + (l4 << 2)) * H_SZ + (w << 6) + l15;

    // prologue: z(0), z(1) in flight; h0 = 0
    f32x4 zA[4], zB[4];
    #pragma unroll
    for (int t = 0; t < 4; ++t) {
        zA[t] = *(const f32x4*)(zp + t * 256);
        zB[t] = *(const f32x4*)(zp + t * 256 + SBH);
    }
    bf16x8 ah[4], al[4];
    #pragma unroll
    for (int c = 0; c < 4; ++c) { ah[c] = (bf16x8){0,0,0,0,0,0,0,0}; al[c] = ah[c]; }
    float tl[4][4];
    union U { unsigned u[4]; bf16x8 v; };

#define BODY(S, P, ZQ)                                                        \
{                                                                             \
    f32x4 acc[4], a2[4], a3[4];                                               \
    _Pragma("unroll")                                                         \
    for (int t = 0; t < 4; ++t) {                                             \
        acc[t] = ZQ[t];                                                       \
        a2[t] = (f32x4){0.f,0.f,0.f,0.f};  a3[t] = a2[t];                     \
    }                                                                         \
    /* prefetch z(S+2) (clamped; value unused on last steps) */               \
    { int sp = (S) + 2; if (sp > S_LEN - 1) sp = S_LEN - 1;                   \
      const float* zs = zp + (size_t)sp * SBH;                                \
      _Pragma("unroll")                                                       \
      for (int t = 0; t < 4; ++t) ZQ[t] = *(const f32x4*)(zs + t * 256); }    \
    _Pragma("unroll")                                                         \
    for (int c = 0; c < 4; ++c) {                                             \
        _Pragma("unroll")                                                     \
        for (int t = 0; t < 4; ++t) {                                         \
            acc[t] = MFMA(ah[c], w2h[t][c], acc[t]);                          \
            a2[t]  = MFMA(al[c], w2h[t][c], a2[t]);                           \
            a3[t]  = MFMA(ah[c], w2l[t][c], a3[t]);                           \
        }                                                                     \
    }                                                                         \
    float* po = out + (size_t)(S) * SBH + obase;                              \
    _Pragma("unroll")                                                         \
    for (int t = 0; t < 4; ++t) {                                             \
        _Pragma("unroll")                                                     \
        for (int r = 0; r < 4; ++r) {                                         \
            float a = (acc[t][r] + a2[t][r]) + a3[t][r];                      \
            float tt = 1.0f - 2.0f * __builtin_amdgcn_rcpf(1.0f + __expf(2.0f*a)); \
            tl[t][r] = tt;                                                    \
            po[(size_t)r * H_SZ + t * 16] = tt;                               \
            *(float*)((char*)hplane[P] + wb[t][r]) = tt;                      \
        }                                                                     \
    }                                                                         \
    LDS_BARRIER();                                                            \
    /* rebuild hi/lo A-fragments from the f32 plane (trunc split) */          \
    _Pragma("unroll")                                                         \
    for (int c = 0; c < 4; ++c) {                                             \
        uint4 d0 = *(const uint4*)((const char*)hplane[P] + rb[c][0]);        \
        uint4 d1 = *(const uint4*)((const char*)hplane[P] + rb[c][1]);        \
        U uh, ul;                                                             \
        uh.u[0] = __builtin_amdgcn_perm(d0.y, d0.x, 0x07060302u);             \
        uh.u[1] = __builtin_amdgcn_perm(d0.w, d0.z, 0x07060302u);             \
        uh.u[2] = __builtin_amdgcn_perm(d1.y, d1.x, 0x07060302u);             \
        uh.u[3] = __builtin_amdgcn_perm(d1.w, d1.z, 0x07060302u);             \
        unsigned e0 = fbits(fval(d0.x) - fval(d0.x & 0xffff0000u));           \
        unsigned e1 = fbits(fval(d0.y) - fval(d0.y & 0xffff0000u));           \
        unsigned e2 = fbits(fval(d0.z) - fval(d0.z & 0xffff0000u));           \
        unsigned e3 = fbits(fval(d0.w) - fval(d0.w & 0xffff0000u));           \
        unsigned e4 = fbits(fval(d1.x) - fval(d1.x & 0xffff0000u));           \
        unsigned e5 = fbits(fval(d1.y) - fval(d1.y & 0xffff0000u));           \
        unsigned e6 = fbits(fval(d1.z) - fval(d1.z & 0xffff0000u));           \
        unsigned e7 = fbits(fval(d1.w) - fval(d1.w & 0xffff0000u));           \
        ul.u[0] = __builtin_amdgcn_perm(e1, e0, 0x07060302u);                 \
        ul.u[1] = __builtin_amdgcn_perm(e3, e2, 0x07060302u);                 \
        ul.u[2] = __builtin_amdgcn_perm(e5, e4, 0x07060302u);                 \
        ul.u[3] = __builtin_amdgcn_perm(e7, e6, 0x07060302u);                 \
        ah[c] = uh.v;  al[c] = ul.v;                                          \
    }                                                                         \
}

    for (int s2 = 0; s2 < S_LEN; s2 += 2) {
        BODY(s2,     0, zA);
        BODY(s2 + 1, 1, zB);
    }
#undef BODY

    // h_last (f32 values of step S_LEN-1 held in tl)
    {
        float* po = out + (size_t)S_LEN * SBH + obase;
        #pragma unroll
        for (int t = 0; t < 4; ++t)
            #pragma unroll
            for (int r = 0; r < 4; ++r)
                po[(size_t)r * H_SZ + t * 16] = tl[t][r];
    }
}

extern "C" void kernel_launch(void* const* d_in, const int* in_sizes, int n_in,
                              void* d_out, int out_size, void* d_ws, size_t ws_size,
                              hipStream_t stream) {
    const float* x  = (const float*)d_in[0];
    const float* W1 = (const float*)d_in[1];
    const float* b1 = (const float*)d_in[2];
    const float* W2 = (const float*)d_in[3];
    const float* b2 = (const float*)d_in[4];
    float* out = (float*)d_out;

    // Phase 1: z into the h_seq region of out (fragment layout, slab-aligned)
    rnn_prepass<<<dim3(S_LEN * NTILE), dim3(BLK1), 0, stream>>>(x, W1, b1, b2, out);
    // Phase 2: serial recurrence, overwrites z with h_seq, appends h_last
    rnn_recur<<<dim3(NTILE), dim3(BLK2), 0, stream>>>(W2, out, out);
}

// Round 7
// 1477.103 us; speedup vs baseline: 1.9494x; 1.9494x over previous
//
#include <hip/hip_runtime.h>
#include <math.h>

// Elman RNN, two-phase.
//   Phase 1 (parallel): z = x*W1^T + b1 + b2, f32-exact (3-product hi/lo
//     bf16 MFMA), stored in MFMA C-fragment order INTO the h_seq region of
//     d_out (slab (s,tile) = exactly the 8KB h_seq(s,tile) later overwrites;
//     z(s) is consumed from registers 2 steps before h_seq(s) is written).
//     One block handles 8 steps of one tile to amortize the W1 split.
//   Phase 2 (serial, 32 blocks x 8 waves): h_t = tanh(h_{t-1}*W2^T + z_t).
//     R4-PROVEN STRUCTURE: wave w owns units [16w,16w+16); h staged as
//     separate hi/lo bf16 short planes, PACKED ON WRITE (read side is pure
//     ds_read_b128 -- r6's read-side rebuild put ~96 VALU on the critical
//     path and 2 waves exposed all latency: 1.17us/step vs r4's 633ns).
//     R5 LESSON: per-step h error must stay ~1e-6 (amplification ~3000x
//     over 2048 steps) -> trunc hi/lo splits + 3 products:
//       W2hi*h_hi + W2lo*h_hi + W2hi*h_lo   (lo*lo dropped).
//     z prefetched 2 steps ahead (1 dwordx4/lane); one raw s_barrier+lgkmcnt
//     per step; h_seq global stores never drained in-loop.

#define S_LEN 2048
#define B_SZ  512
#define I_SZ  64
#define H_SZ  128
#define BT    16
#define NTILE 32
#define BLK   512
#define SPB   8                    // prepass: steps per block
#define SBH   (B_SZ * H_SZ)        // floats per step-slab in out

typedef short bf16x8 __attribute__((ext_vector_type(8)));
typedef float f32x4  __attribute__((ext_vector_type(4)));

#define MFMA(A, B, C) __builtin_amdgcn_mfma_f32_16x16x32_bf16((A), (B), (C), 0, 0, 0)

#define LDS_BARRIER()                                        \
    asm volatile("s_waitcnt lgkmcnt(0)" ::: "memory");       \
    __builtin_amdgcn_s_barrier();                            \
    asm volatile("" ::: "memory")

__device__ __forceinline__ unsigned fbits(float v) {
    union { float f; unsigned u; } x; x.f = v; return x.u;
}
__device__ __forceinline__ float fval(unsigned u) {
    union { float f; unsigned u; } x; x.u = u; return x.f;
}
__device__ __forceinline__ unsigned short bf_trunc(float v) {
    return (unsigned short)(fbits(v) >> 16);
}
// split 8 consecutive floats into hi/lo bf16 fragments (trunc, r4-proven)
__device__ __forceinline__ void split8t(float4 a, float4 b, bf16x8* hi, bf16x8* lo) {
    float v[8] = {a.x, a.y, a.z, a.w, b.x, b.y, b.z, b.w};
    #pragma unroll
    for (int j = 0; j < 8; ++j) {
        unsigned short h = bf_trunc(v[j]);
        (*hi)[j] = (short)h;
        (*lo)[j] = (short)bf_trunc(v[j] - fval(((unsigned)h) << 16));
    }
}

// ---------------- Phase 1: z = x*W1^T + b1 + b2 (fragment layout) ----------
__global__ __launch_bounds__(BLK) void rnn_prepass(
    const float* __restrict__ x,
    const float* __restrict__ W1,
    const float* __restrict__ b1,
    const float* __restrict__ b2,
    float* __restrict__ z)
{
    const int tid  = threadIdx.x;
    const int lane = tid & 63;
    const int w    = tid >> 6;
    const int l15  = lane & 15;
    const int l4   = lane >> 4;
    const int unit = (w << 4) + l15;
    const int bid  = blockIdx.x;
    const int tile = bid & (NTILE - 1);
    const int s0   = (bid >> 5) * SPB;
    const int b0   = tile << 4;

    // W1 B-fragments hi/lo, split ONCE per 8 steps
    bf16x8 w1h[2], w1l[2];
    #pragma unroll
    for (int c = 0; c < 2; ++c) {
        const float* wr = W1 + unit * I_SZ + 32 * c + l4 * 8;
        split8t(*(const float4*)wr, *(const float4*)(wr + 4), &w1h[c], &w1l[c]);
    }
    const float zb = b1[unit] + b2[unit];

    for (int i = 0; i < SPB; ++i) {
        const int s = s0 + i;
        const float* xr = x + ((size_t)s * B_SZ + b0 + l15) * I_SZ + l4 * 8;
        bf16x8 xh[2], xl[2];
        #pragma unroll
        for (int c = 0; c < 2; ++c)
            split8t(*(const float4*)(xr + 32 * c), *(const float4*)(xr + 32 * c + 4),
                    &xh[c], &xl[c]);

        f32x4 acc  = {zb, zb, zb, zb};
        f32x4 acc2 = {0.f, 0.f, 0.f, 0.f};
        acc  = MFMA(xh[0], w1h[0], acc);   acc  = MFMA(xh[1], w1h[1], acc);
        acc2 = MFMA(xl[0], w1h[0], acc2);  acc2 = MFMA(xl[1], w1h[1], acc2);
        acc2 = MFMA(xh[0], w1l[0], acc2);  acc2 = MFMA(xh[1], w1l[1], acc2);
        acc += acc2;

        // fragment-order store: subtile w of slab (s,tile)
        *(f32x4*)(z + ((size_t)(s * NTILE + tile) * 8 + w) * 256 + lane * 4) = acc;
    }
}

// ---------------- Phase 2: serial recurrence (8 waves / tile) --------------
__global__ __launch_bounds__(BLK, 2) void rnn_recur(
    const float* __restrict__ W2,
    const float* zr,              // z region (fragment layout), aliases out
    float* out)
{
    const int tid  = threadIdx.x;
    const int lane = tid & 63;
    const int w    = tid >> 6;        // wave -> units [16w, 16w+16)
    const int l15  = lane & 15;
    const int l4   = lane >> 4;
    const int unit = (w << 4) + l15;
    const int tile = blockIdx.x;
    const int b0   = tile << 4;

    __shared__ short hp_hi[2][BT * H_SZ];   // 2 x 4 KiB, XOR-swizzled
    __shared__ short hp_lo[2][BT * H_SZ];

    // W2 B-fragments hi/lo (AGPR-parking is fine: MFMA reads AGPRs natively)
    bf16x8 w2h[4], w2l[4];
    #pragma unroll
    for (int c = 0; c < 4; ++c) {
        const float* wr = W2 + unit * H_SZ + 32 * c + l4 * 8;
        split8t(*(const float4*)wr, *(const float4*)(wr + 4), &w2h[c], &w2l[c]);
    }

    // LDS byte offsets; swizzle: byte ^= (row&7)<<4, 16B-granular, bijective
    int hro[4], woh[4];
    #pragma unroll
    for (int c = 0; c < 4; ++c)                    // read: row l15, chunk c
        hro[c] = l15 * 256 + ((64 * c + 16 * l4) ^ ((l15 & 7) << 4));
    #pragma unroll
    for (int r = 0; r < 4; ++r) {                  // write: row 4*l4+r, col unit
        int row = (l4 << 2) + r;
        woh[r] = row * 256 + ((unit * 2) ^ ((row & 7) << 4));
    }

    const float* zp = zr + (size_t)tile * 2048 + (size_t)w * 256 + lane * 4;
    float* po = out + (size_t)(b0 + (l4 << 2)) * H_SZ + unit;   // row 4*l4, +r*H

    // prologue: z(0), z(1) in flight; h0 = 0
    f32x4 zA = *(const f32x4*)(zp);
    f32x4 zB = *(const f32x4*)(zp + SBH);

    bf16x8 ah[4], al[4];
    #pragma unroll
    for (int c = 0; c < 4; ++c) { ah[c] = (bf16x8){0,0,0,0,0,0,0,0}; al[c] = ah[c]; }
    float tl[4] = {0.f, 0.f, 0.f, 0.f};

#define BODY(S, P, ZQ)                                                        \
{                                                                             \
    f32x4 acc  = ZQ;                                                          \
    f32x4 acc2 = {0.f, 0.f, 0.f, 0.f};                                        \
    f32x4 acc3 = {0.f, 0.f, 0.f, 0.f};                                        \
    /* prefetch z(S+2) (clamped; value unused on the last two bodies) */      \
    { int sp = (S) + 2; if (sp > S_LEN - 1) sp = S_LEN - 1;                   \
      ZQ = *(const f32x4*)(zp + (size_t)sp * SBH); }                          \
    acc  = MFMA(ah[0], w2h[0], acc);   acc2 = MFMA(al[0], w2h[0], acc2);      \
    acc3 = MFMA(ah[0], w2l[0], acc3);                                         \
    acc  = MFMA(ah[1], w2h[1], acc);   acc2 = MFMA(al[1], w2h[1], acc2);      \
    acc3 = MFMA(ah[1], w2l[1], acc3);                                         \
    acc  = MFMA(ah[2], w2h[2], acc);   acc2 = MFMA(al[2], w2h[2], acc2);      \
    acc3 = MFMA(ah[2], w2l[2], acc3);                                         \
    acc  = MFMA(ah[3], w2h[3], acc);   acc2 = MFMA(al[3], w2h[3], acc2);      \
    acc3 = MFMA(ah[3], w2l[3], acc3);                                         \
    acc = (acc + acc2) + acc3;                                                \
    _Pragma("unroll")                                                         \
    for (int r = 0; r < 4; ++r) {                                             \
        float a = acc[r];                                                     \
        float t = 1.0f - 2.0f * __builtin_amdgcn_rcpf(1.0f + __expf(2.0f*a)); \
        tl[r] = t;                                                            \
        po[(size_t)(S) * SBH + (size_t)r * H_SZ] = t;                         \
        unsigned short hi = bf_trunc(t);                                      \
        *(short*)((char*)hp_hi[P] + woh[r]) = (short)hi;                      \
        *(short*)((char*)hp_lo[P] + woh[r]) =                                 \
            (short)bf_trunc(t - fval(((unsigned)hi) << 16));                  \
    }                                                                         \
    LDS_BARRIER();                                                            \
    _Pragma("unroll")                                                         \
    for (int c = 0; c < 4; ++c) {                                             \
        ah[c] = *(const bf16x8*)((const char*)hp_hi[P] + hro[c]);             \
        al[c] = *(const bf16x8*)((const char*)hp_lo[P] + hro[c]);             \
    }                                                                         \
}

    for (int s2 = 0; s2 < S_LEN; s2 += 2) {
        BODY(s2,     0, zA);
        BODY(s2 + 1, 1, zB);
    }
#undef BODY

    // h_last (step S_LEN-1 values held in tl)
    #pragma unroll
    for (int r = 0; r < 4; ++r)
        po[(size_t)S_LEN * SBH + (size_t)r * H_SZ] = tl[r];
}

extern "C" void kernel_launch(void* const* d_in, const int* in_sizes, int n_in,
                              void* d_out, int out_size, void* d_ws, size_t ws_size,
                              hipStream_t stream) {
    const float* x  = (const float*)d_in[0];
    const float* W1 = (const float*)d_in[1];
    const float* b1 = (const float*)d_in[2];
    const float* W2 = (const float*)d_in[3];
    const float* b2 = (const float*)d_in[4];
    float* out = (float*)d_out;

    // Phase 1: z into the h_seq region of out (fragment layout, slab-aligned)
    rnn_prepass<<<dim3((S_LEN / SPB) * NTILE), dim3(BLK), 0, stream>>>(x, W1, b1, b2, out);
    // Phase 2: serial recurrence, overwrites z with h_seq, appends h_last
    rnn_recur<<<dim3(NTILE), dim3(BLK), 0, stream>>>(W2, out, out);
}